// Round 6
// baseline (294.253 us; speedup 1.0000x reference)
//
#include <hip/hip_runtime.h>

#define N0 6400
#define NC 256
#define WW 80

using half8   = __attribute__((ext_vector_type(8))) _Float16;
using floatx4 = __attribute__((ext_vector_type(4))) float;
#define GLOBAL_AS __attribute__((address_space(1)))
#define LDS_AS    __attribute__((address_space(3)))

__device__ __forceinline__ unsigned long long packvi(float v, int i) {
    return ((unsigned long long)__float_as_uint(v) << 32) | (unsigned int)i;
}

// ---------------- K1: partial sumsq over channel halves + zero-inits ----
__global__ __launch_bounds__(256) void knorm(const float* __restrict__ f0,
                                             const float* __restrict__ f1,
                                             float* __restrict__ snorm,
                                             float* __restrict__ rowsum,
                                             float* __restrict__ colsum,
                                             unsigned long long* __restrict__ rowbest,
                                             unsigned long long* __restrict__ colbest) {
    int g = blockIdx.x * 256 + threadIdx.x;          // 0..25599
    if (g < N0) {                                    // zero reduction buffers
        rowsum[g] = 0.f; colsum[g] = 0.f;
        rowbest[g] = 0ull; colbest[g] = 0ull;
    }
    int h = (g >= 12800) ? 1 : 0;
    int j = g - h * 12800;                           // 0..12799
    const float* src = (j < N0) ? f0 : f1;
    int n = (j < N0) ? j : (j - N0);
    int c0 = h * 128;
    float s = 0.f;
#pragma unroll 8
    for (int c = 0; c < 128; ++c) {
        float v = src[(c0 + c) * N0 + n];
        s += v * v;
    }
    snorm[g] = s;
}

// -------- K2: transpose (C,N)->(N,256) fp16, normalized; z selects f0/f1
__global__ __launch_bounds__(256) void ktrans(const float* __restrict__ f0,
                                              const float* __restrict__ f1,
                                              const float* __restrict__ snorm,
                                              _Float16* __restrict__ A2,
                                              _Float16* __restrict__ B2) {
    __shared__ float tile[32][33];
    const float* src = blockIdx.z ? f1 : f0;
    _Float16* dst    = blockIdx.z ? B2 : A2;
    int t = threadIdx.x;
    int n0 = blockIdx.x * 32, c0 = blockIdx.y * 32;
    int tx = t & 31, ty = t >> 5;                    // 32 x 8
#pragma unroll
    for (int u = 0; u < 4; ++u)
        tile[ty + u * 8][tx] = src[(c0 + ty + u * 8) * N0 + n0 + tx];
    __syncthreads();
    int row = t >> 3;            // 0..31 (local n)
    int cg  = (t & 7) * 4;       // 0..28 (local c, groups of 4)
    int n = n0 + row;
    int j = (blockIdx.z ? N0 : 0) + n;
    float s = snorm[j] + snorm[12800 + j];
    float iv = 1.0f / fmaxf(sqrtf(s), 1e-12f);
    union { ushort4 u4; _Float16 h[4]; } pk;
#pragma unroll
    for (int u = 0; u < 4; ++u)
        pk.h[u] = (_Float16)(tile[cg + u][row] * iv);
    *(ushort4*)&dst[n * NC + c0 + cg] = pk.u4;
}

// ---------------- staging: 128 rows x 128 k-values (half-K chunk) -------
__device__ __forceinline__ void stage_chunk(const _Float16* __restrict__ G,
                                            unsigned short* lds, int r0, int kc,
                                            int tid) {
    int rl = tid >> 3;                               // 0..31
    int ch = ((tid & 7) ^ (rl & 7)) * 8;             // swizzled chunk (halves)
#pragma unroll
    for (int kk = 0; kk < 2; ++kk)
#pragma unroll
        for (int g = 0; g < 4; ++g) {
            const _Float16* ga = G + (r0 + g * 32 + rl) * NC + kc * 128 + kk * 64 + ch;
            __builtin_amdgcn_global_load_lds((const GLOBAL_AS unsigned int*)ga,
                (LDS_AS unsigned int*)&lds[kk * 8192 + g * 2048 + tid * 8], 16, 0, 0);
        }
}

// ---------------- half-K compute: 4 s-steps, 64 MFMA/wave ---------------
template<bool HI>
__device__ __forceinline__ void compute_half(const unsigned short* bbuf,
                                             const unsigned short* abufHi,
                                             const half8 aflo[4][4],
                                             int lane, int wm, int wn,
                                             floatx4 acc[4][4]) {
    int q = lane >> 4;
#pragma unroll
    for (int s = 0; s < 4; ++s) {
        int c = s * 4 + q, kk = c >> 3, cq = c & 7;
        half8 af[4], bf[4];
#pragma unroll
        for (int mt = 0; mt < 4; ++mt) {
            int rb = wn * 64 + mt * 16 + (lane & 15);
            bf[mt] = *(const half8*)&bbuf[kk * 8192 + rb * 64 + ((cq ^ (rb & 7)) * 8)];
        }
#pragma unroll
        for (int mt = 0; mt < 4; ++mt) {
            if (HI) {
                int ra = wm * 64 + mt * 16 + (lane & 15);
                af[mt] = *(const half8*)&abufHi[kk * 8192 + ra * 64 + ((cq ^ (ra & 7)) * 8)];
            } else {
                af[mt] = aflo[mt][s];
            }
        }
#pragma unroll
        for (int mt = 0; mt < 4; ++mt)
#pragma unroll
            for (int nt = 0; nt < 4; ++nt)
                acc[mt][nt] = __builtin_amdgcn_mfma_f32_16x16x32_f16(
                    af[mt], bf[nt], acc[mt][nt], 0, 0, 0);
    }
}

// ---------------- shared prologue: stage A, hoist k-low frags -----------
__device__ __forceinline__ void gemm_prologue(const _Float16* __restrict__ A2,
                                              unsigned short* regA,
                                              unsigned short* regB,
                                              int i0, int tid, int lane,
                                              int wm, half8 aflo[4][4]) {
    int q = lane >> 4;
    stage_chunk(A2, regB, i0, 0, tid);               // A k-low (transient)
    stage_chunk(A2, regA, i0, 1, tid);               // A k-high (persistent)
    __syncthreads();
#pragma unroll
    for (int mt = 0; mt < 4; ++mt)
#pragma unroll
        for (int s = 0; s < 4; ++s) {
            int c = s * 4 + q, kk = c >> 3, cq = c & 7;
            int ra = wm * 64 + mt * 16 + (lane & 15);
            aflo[mt][s] = *(const half8*)&regB[kk * 8192 + ra * 64 + ((cq ^ (ra & 7)) * 8)];
        }
    __syncthreads();                                 // regB free
}

// ======================= PATH P: partials, no global atomics ============
__global__ __launch_bounds__(256, 2) void kgemm1P(const _Float16* __restrict__ A2,
                                                  const _Float16* __restrict__ B2,
                                                  float* __restrict__ rowpart,
                                                  float* __restrict__ colpart) {
    __shared__ __align__(16) unsigned short lds[32768];   // 64 KiB
    __shared__ float cs[2][128];
    __shared__ float rs[2][128];
    unsigned short* regA = lds;
    unsigned short* regB = lds + 16384;
    int tid = threadIdx.x, lane = tid & 63, wave = tid >> 6;
    int wm = wave & 1, wn = wave >> 1, q = lane >> 4;
    int i0 = blockIdx.x * 128, jp = blockIdx.y * 640;

    half8 aflo[4][4];
    gemm_prologue(A2, regA, regB, i0, tid, lane, wm, aflo);

    float rsum[4][4] = {};
    for (int jt = 0; jt < 5; ++jt) {
        stage_chunk(B2, regB, jp + jt * 128, 0, tid);
        __syncthreads();
        floatx4 acc[4][4] = {};
        compute_half<false>(regB, regA, aflo, lane, wm, wn, acc);
        __syncthreads();
        stage_chunk(B2, regB, jp + jt * 128, 1, tid);
        __syncthreads();
        compute_half<true>(regB, regA, aflo, lane, wm, wn, acc);

        float csum[4] = {0.f, 0.f, 0.f, 0.f};
#pragma unroll
        for (int mt = 0; mt < 4; ++mt)
#pragma unroll
            for (int r = 0; r < 4; ++r) {
                float rv = 0.f;
#pragma unroll
                for (int nt = 0; nt < 4; ++nt) {
                    float e = __expf(10.0f * acc[mt][nt][r]);
                    rv += e; csum[nt] += e;
                }
                rsum[mt][r] += rv;
            }
#pragma unroll
        for (int nt = 0; nt < 4; ++nt) {
            csum[nt] += __shfl_xor(csum[nt], 16);
            csum[nt] += __shfl_xor(csum[nt], 32);
        }
        if (lane < 16)
#pragma unroll
            for (int nt = 0; nt < 4; ++nt)
                cs[wm][wn * 64 + nt * 16 + lane] = csum[nt];
        __syncthreads();                             // regB reads done + cs ready
        if (tid < 128)
            colpart[blockIdx.x * N0 + jp + jt * 128 + tid] = cs[0][tid] + cs[1][tid];
    }
#pragma unroll
    for (int mt = 0; mt < 4; ++mt)
#pragma unroll
        for (int r = 0; r < 4; ++r) {
            float v = rsum[mt][r];
            v += __shfl_xor(v, 1);
            v += __shfl_xor(v, 2);
            v += __shfl_xor(v, 4);
            v += __shfl_xor(v, 8);
            if ((lane & 15) == 0)
                rs[wn][wm * 64 + mt * 16 + q * 4 + r] = v;
        }
    __syncthreads();
    if (tid < 128)
        rowpart[blockIdx.y * N0 + i0 + tid] = rs[0][tid] + rs[1][tid];
}

__global__ __launch_bounds__(256) void kreduce(const float* __restrict__ rowpart,
                                               const float* __restrict__ colpart,
                                               float* __restrict__ rowsum,
                                               float* __restrict__ colsum) {
    int t = blockIdx.x * 256 + threadIdx.x;          // 0..12799
    if (t < N0) {
        float s = 0.f;
#pragma unroll
        for (int y = 0; y < 10; ++y) s += rowpart[y * N0 + t];
        rowsum[t] = s;
    } else {
        int j = t - N0;
        float s = 0.f;
#pragma unroll
        for (int x = 0; x < 50; ++x) s += colpart[x * N0 + j];
        colsum[j] = s;
    }
}

__global__ __launch_bounds__(256, 2) void kgemm2P(const _Float16* __restrict__ A2,
                                                  const _Float16* __restrict__ B2,
                                                  const float* __restrict__ rowsum,
                                                  const float* __restrict__ colsum,
                                                  float* __restrict__ P,
                                                  unsigned long long* __restrict__ rowbpart,
                                                  unsigned long long* __restrict__ colbpart) {
    __shared__ __align__(16) unsigned short lds[32768];   // 64 KiB
    __shared__ unsigned long long cbst[2][128];
    __shared__ unsigned long long rbst[2][128];
    unsigned short* regA = lds;
    unsigned short* regB = lds + 16384;
    int tid = threadIdx.x, lane = tid & 63, wave = tid >> 6;
    int wm = wave & 1, wn = wave >> 1, q = lane >> 4;
    int i0 = blockIdx.x * 128, jp = blockIdx.y * 640;

    half8 aflo[4][4];
    gemm_prologue(A2, regA, regB, i0, tid, lane, wm, aflo);

    float ir[4][4];
#pragma unroll
    for (int mt = 0; mt < 4; ++mt) {
        float4 v4 = *(const float4*)&rowsum[i0 + wm * 64 + mt * 16 + q * 4];
        ir[mt][0] = 1.0f / v4.x; ir[mt][1] = 1.0f / v4.y;
        ir[mt][2] = 1.0f / v4.z; ir[mt][3] = 1.0f / v4.w;
    }

    unsigned long long rbv[4][4] = {};
    for (int jt = 0; jt < 5; ++jt) {
        stage_chunk(B2, regB, jp + jt * 128, 0, tid);
        __syncthreads();
        floatx4 acc[4][4] = {};
        compute_half<false>(regB, regA, aflo, lane, wm, wn, acc);
        __syncthreads();
        stage_chunk(B2, regB, jp + jt * 128, 1, tid);
        __syncthreads();
        compute_half<true>(regB, regA, aflo, lane, wm, wn, acc);

        int cb0 = jp + jt * 128 + wn * 64 + (lane & 15);
        float ic[4];
#pragma unroll
        for (int nt = 0; nt < 4; ++nt) ic[nt] = 1.0f / colsum[cb0 + nt * 16];

        unsigned long long colb[4] = {0ull, 0ull, 0ull, 0ull};
#pragma unroll
        for (int mt = 0; mt < 4; ++mt) {
            int rb0 = i0 + wm * 64 + mt * 16 + q * 4;
#pragma unroll
            for (int r = 0; r < 4; ++r) {
                int row = rb0 + r;
#pragma unroll
                for (int nt = 0; nt < 4; ++nt) {
                    float pv = __expf(20.0f * acc[mt][nt][r]) * ir[mt][r] * ic[nt];
                    __builtin_nontemporal_store(pv, &P[row * N0 + cb0 + nt * 16]);
                    unsigned long long pr = packvi(pv, cb0 + nt * 16);
                    if (pr > rbv[mt][r]) rbv[mt][r] = pr;
                    unsigned long long pc = packvi(pv, row);
                    if (pc > colb[nt]) colb[nt] = pc;
                }
            }
        }
#pragma unroll
        for (int nt = 0; nt < 4; ++nt) {
            unsigned long long o = __shfl_xor(colb[nt], 16);
            if (o > colb[nt]) colb[nt] = o;
            o = __shfl_xor(colb[nt], 32);
            if (o > colb[nt]) colb[nt] = o;
        }
        if (lane < 16)
#pragma unroll
            for (int nt = 0; nt < 4; ++nt)
                cbst[wm][wn * 64 + nt * 16 + lane] = colb[nt];
        __syncthreads();
        if (tid < 128) {
            unsigned long long a = cbst[0][tid], b = cbst[1][tid];
            colbpart[blockIdx.x * N0 + jp + jt * 128 + tid] = (a > b) ? a : b;
        }
    }
#pragma unroll
    for (int mt = 0; mt < 4; ++mt)
#pragma unroll
        for (int r = 0; r < 4; ++r) {
            unsigned long long v = rbv[mt][r];
#pragma unroll
            for (int s = 1; s < 16; s <<= 1) {
                unsigned long long o = __shfl_xor(v, s);
                if (o > v) v = o;
            }
            if ((lane & 15) == 0)
                rbst[wn][wm * 64 + mt * 16 + q * 4 + r] = v;
        }
    __syncthreads();
    if (tid < 128) {
        unsigned long long a = rbst[0][tid], b = rbst[1][tid];
        rowbpart[blockIdx.y * N0 + i0 + tid] = (a > b) ? a : b;
    }
}

__global__ __launch_bounds__(256) void kmatchP(const unsigned long long* __restrict__ rowbpart,
                                               const unsigned long long* __restrict__ colbpart,
                                               float* __restrict__ out) {
    int i = blockIdx.x * 256 + threadIdx.x;      // 0..6399
    unsigned long long rb = 0ull;
#pragma unroll
    for (int y = 0; y < 10; ++y) {
        unsigned long long v = rowbpart[y * N0 + i];
        if (v > rb) rb = v;
    }
    float conf = __uint_as_float((unsigned int)(rb >> 32));
    int jj = (int)(rb & 0xffffffffu);
    unsigned long long cb = 0ull;
    for (int x = 0; x < 50; ++x) {
        unsigned long long v = colbpart[x * N0 + jj];
        if (v > cb) cb = v;
    }
    int i2 = (int)(cb & 0xffffffffu);
    bool valid = (i2 == i) && (conf > 0.2f);
    float vf = valid ? 1.0f : 0.0f;

    float* mk0   = out + 40960000;
    float* mk1   = out + 40972800;
    float* mconf = out + 40985600;
    float* vout  = out + 40992000;
    mk0[i * 2 + 0] = vf * (float)(i % WW);
    mk0[i * 2 + 1] = vf * (float)(i / WW);
    mk1[i * 2 + 0] = vf * (float)(jj % WW);
    mk1[i * 2 + 1] = vf * (float)(jj / WW);
    mconf[i] = valid ? conf : 0.0f;
    vout[i]  = vf;
}

// ======================= PATH A: proven round-4 atomic kernels ==========
__global__ __launch_bounds__(256, 2) void kgemm1A(const _Float16* __restrict__ A2,
                                                  const _Float16* __restrict__ B2,
                                                  float* __restrict__ rowsum,
                                                  float* __restrict__ colsum) {
    __shared__ __align__(16) unsigned short lds[32768];
    unsigned short* regA = lds;
    unsigned short* regB = lds + 16384;
    int tid = threadIdx.x, lane = tid & 63, wave = tid >> 6;
    int wm = wave & 1, wn = wave >> 1, q = lane >> 4;
    int i0 = blockIdx.x * 128, jp = blockIdx.y * 640;

    half8 aflo[4][4];
    gemm_prologue(A2, regA, regB, i0, tid, lane, wm, aflo);

    float rsum[4][4] = {};
    for (int jt = 0; jt < 5; ++jt) {
        stage_chunk(B2, regB, jp + jt * 128, 0, tid);
        __syncthreads();
        floatx4 acc[4][4] = {};
        compute_half<false>(regB, regA, aflo, lane, wm, wn, acc);
        __syncthreads();
        stage_chunk(B2, regB, jp + jt * 128, 1, tid);
        __syncthreads();
        compute_half<true>(regB, regA, aflo, lane, wm, wn, acc);

        float csum[4] = {0.f, 0.f, 0.f, 0.f};
#pragma unroll
        for (int mt = 0; mt < 4; ++mt)
#pragma unroll
            for (int r = 0; r < 4; ++r) {
                float rv = 0.f;
#pragma unroll
                for (int nt = 0; nt < 4; ++nt) {
                    float e = __expf(10.0f * acc[mt][nt][r]);
                    rv += e; csum[nt] += e;
                }
                rsum[mt][r] += rv;
            }
#pragma unroll
        for (int nt = 0; nt < 4; ++nt) {
            csum[nt] += __shfl_xor(csum[nt], 16);
            csum[nt] += __shfl_xor(csum[nt], 32);
        }
        if (lane < 16)
#pragma unroll
            for (int nt = 0; nt < 4; ++nt)
                atomicAdd(&colsum[jp + jt * 128 + wn * 64 + nt * 16 + lane], csum[nt]);
        __syncthreads();
    }
#pragma unroll
    for (int mt = 0; mt < 4; ++mt)
#pragma unroll
        for (int r = 0; r < 4; ++r) {
            float v = rsum[mt][r];
            v += __shfl_xor(v, 1);
            v += __shfl_xor(v, 2);
            v += __shfl_xor(v, 4);
            v += __shfl_xor(v, 8);
            if ((lane & 15) == 0)
                atomicAdd(&rowsum[i0 + wm * 64 + mt * 16 + q * 4 + r], v);
        }
}

__global__ __launch_bounds__(256, 2) void kgemm2A(const _Float16* __restrict__ A2,
                                                  const _Float16* __restrict__ B2,
                                                  const float* __restrict__ rowsum,
                                                  const float* __restrict__ colsum,
                                                  float* __restrict__ P,
                                                  unsigned long long* __restrict__ rowbest,
                                                  unsigned long long* __restrict__ colbest) {
    __shared__ __align__(16) unsigned short lds[32768];
    unsigned short* regA = lds;
    unsigned short* regB = lds + 16384;
    int tid = threadIdx.x, lane = tid & 63, wave = tid >> 6;
    int wm = wave & 1, wn = wave >> 1, q = lane >> 4;
    int i0 = blockIdx.x * 128, jp = blockIdx.y * 640;

    half8 aflo[4][4];
    gemm_prologue(A2, regA, regB, i0, tid, lane, wm, aflo);

    float ir[4][4];
#pragma unroll
    for (int mt = 0; mt < 4; ++mt) {
        float4 v4 = *(const float4*)&rowsum[i0 + wm * 64 + mt * 16 + q * 4];
        ir[mt][0] = 1.0f / v4.x; ir[mt][1] = 1.0f / v4.y;
        ir[mt][2] = 1.0f / v4.z; ir[mt][3] = 1.0f / v4.w;
    }

    unsigned long long rbv[4][4] = {};
    for (int jt = 0; jt < 5; ++jt) {
        stage_chunk(B2, regB, jp + jt * 128, 0, tid);
        __syncthreads();
        floatx4 acc[4][4] = {};
        compute_half<false>(regB, regA, aflo, lane, wm, wn, acc);
        __syncthreads();
        stage_chunk(B2, regB, jp + jt * 128, 1, tid);
        __syncthreads();
        compute_half<true>(regB, regA, aflo, lane, wm, wn, acc);

        int cb0 = jp + jt * 128 + wn * 64 + (lane & 15);
        float ic[4];
#pragma unroll
        for (int nt = 0; nt < 4; ++nt) ic[nt] = 1.0f / colsum[cb0 + nt * 16];

        unsigned long long colb[4] = {0ull, 0ull, 0ull, 0ull};
#pragma unroll
        for (int mt = 0; mt < 4; ++mt) {
            int rb0 = i0 + wm * 64 + mt * 16 + q * 4;
#pragma unroll
            for (int r = 0; r < 4; ++r) {
                int row = rb0 + r;
#pragma unroll
                for (int nt = 0; nt < 4; ++nt) {
                    float pv = __expf(20.0f * acc[mt][nt][r]) * ir[mt][r] * ic[nt];
                    P[row * N0 + cb0 + nt * 16] = pv;
                    unsigned long long pr = packvi(pv, cb0 + nt * 16);
                    if (pr > rbv[mt][r]) rbv[mt][r] = pr;
                    unsigned long long pc = packvi(pv, row);
                    if (pc > colb[nt]) colb[nt] = pc;
                }
            }
        }
#pragma unroll
        for (int nt = 0; nt < 4; ++nt) {
            unsigned long long o = __shfl_xor(colb[nt], 16);
            if (o > colb[nt]) colb[nt] = o;
            o = __shfl_xor(colb[nt], 32);
            if (o > colb[nt]) colb[nt] = o;
        }
        if (lane < 16)
#pragma unroll
            for (int nt = 0; nt < 4; ++nt)
                atomicMax(&colbest[cb0 + nt * 16], colb[nt]);
        __syncthreads();
    }
#pragma unroll
    for (int mt = 0; mt < 4; ++mt)
#pragma unroll
        for (int r = 0; r < 4; ++r) {
            unsigned long long v = rbv[mt][r];
#pragma unroll
            for (int s = 1; s < 16; s <<= 1) {
                unsigned long long o = __shfl_xor(v, s);
                if (o > v) v = o;
            }
            if ((lane & 15) == 0)
                atomicMax(&rowbest[i0 + wm * 64 + mt * 16 + q * 4 + r], v);
        }
}

__global__ __launch_bounds__(256) void kmatchA(const unsigned long long* __restrict__ rowbest,
                                               const unsigned long long* __restrict__ colbest,
                                               float* __restrict__ out) {
    int i = blockIdx.x * 256 + threadIdx.x;      // 0..6399
    unsigned long long rb = rowbest[i];
    float conf = __uint_as_float((unsigned int)(rb >> 32));
    int jj = (int)(rb & 0xffffffffu);
    unsigned long long cb = colbest[jj];
    int i2 = (int)(cb & 0xffffffffu);
    bool valid = (i2 == i) && (conf > 0.2f);
    float vf = valid ? 1.0f : 0.0f;

    float* mk0   = out + 40960000;
    float* mk1   = out + 40972800;
    float* mconf = out + 40985600;
    float* vout  = out + 40992000;
    mk0[i * 2 + 0] = vf * (float)(i % WW);
    mk0[i * 2 + 1] = vf * (float)(i / WW);
    mk1[i * 2 + 0] = vf * (float)(jj % WW);
    mk1[i * 2 + 1] = vf * (float)(jj / WW);
    mconf[i] = valid ? conf : 0.0f;
    vout[i]  = vf;
}

extern "C" void kernel_launch(void* const* d_in, const int* in_sizes, int n_in,
                              void* d_out, int out_size, void* d_ws, size_t ws_size,
                              hipStream_t stream) {
    const float* f0 = (const float*)d_in[0];
    const float* f1 = (const float*)d_in[1];
    float* out = (float*)d_out;

    _Float16* A2 = (_Float16*)d_ws;                  // 6400x256 fp16
    _Float16* B2 = A2 + 6400 * 256;
    float* snorm   = (float*)(B2 + 6400 * 256);      // 25600 partial sumsq
    float* rowsum  = snorm + 25600;                  // 6400
    float* colsum  = rowsum + 6400;                  // 6400
    unsigned long long* rowbest = (unsigned long long*)(colsum + 6400);  // 6400
    unsigned long long* colbest = rowbest + 6400;                        // 6400
    // ---- extended (partials) region, used only if ws_size permits ----
    float* rowpart = (float*)(colbest + 6400);       // 10 x 6400
    float* colpart = rowpart + 10 * 6400;            // 50 x 6400
    unsigned long long* rowbpart =                   // 10 x 6400
        (unsigned long long*)(colpart + 50 * 6400);
    unsigned long long* colbpart = rowbpart + 10 * 6400;   // 50 x 6400
    const size_t WS_NEEDED_P = 11417600;             // bytes incl. partials

    knorm<<<100, 256, 0, stream>>>(f0, f1, snorm,
                                   rowsum, colsum, rowbest, colbest);
    ktrans<<<dim3(200, 8, 2), 256, 0, stream>>>(f0, f1, snorm, A2, B2);

    if (ws_size >= WS_NEEDED_P) {
        kgemm1P<<<dim3(50, 10), 256, 0, stream>>>(A2, B2, rowpart, colpart);
        kreduce<<<50, 256, 0, stream>>>(rowpart, colpart, rowsum, colsum);
        kgemm2P<<<dim3(50, 10), 256, 0, stream>>>(A2, B2, rowsum, colsum,
                                                  out, rowbpart, colbpart);
        kmatchP<<<25, 256, 0, stream>>>(rowbpart, colbpart, out);
    } else {
        kgemm1A<<<dim3(50, 10), 256, 0, stream>>>(A2, B2, rowsum, colsum);
        kgemm2A<<<dim3(50, 10), 256, 0, stream>>>(A2, B2, rowsum, colsum,
                                                  out, rowbest, colbest);
        kmatchA<<<25, 256, 0, stream>>>(rowbest, colbest, out);
    }
}

// Round 8
// 284.950 us; speedup vs baseline: 1.0326x; 1.0326x over previous
//
#include <hip/hip_runtime.h>

#define N0 6400
#define NC 256
#define WW 80

using half8   = __attribute__((ext_vector_type(8))) _Float16;
using floatx4 = __attribute__((ext_vector_type(4))) float;
#define GLOBAL_AS __attribute__((address_space(1)))
#define LDS_AS    __attribute__((address_space(3)))

__device__ __forceinline__ unsigned long long packvi(float v, int i) {
    return ((unsigned long long)__float_as_uint(v) << 32) | (unsigned int)i;
}

// ---------------- K1: partial sumsq over channel halves -----------------
__global__ __launch_bounds__(256) void knorm(const float* __restrict__ f0,
                                             const float* __restrict__ f1,
                                             float* __restrict__ snorm) {
    int g = blockIdx.x * 256 + threadIdx.x;          // 0..25599
    int h = (g >= 12800) ? 1 : 0;
    int j = g - h * 12800;                           // 0..12799
    const float* src = (j < N0) ? f0 : f1;
    int n = (j < N0) ? j : (j - N0);
    int c0 = h * 128;
    float s = 0.f;
#pragma unroll 8
    for (int c = 0; c < 128; ++c) {
        float v = src[(c0 + c) * N0 + n];
        s += v * v;
    }
    snorm[g] = s;
}

// -------- K2: transpose (C,N)->(N,256) fp16, normalized; z selects f0/f1
__global__ __launch_bounds__(256) void ktrans(const float* __restrict__ f0,
                                              const float* __restrict__ f1,
                                              const float* __restrict__ snorm,
                                              _Float16* __restrict__ A2,
                                              _Float16* __restrict__ B2) {
    __shared__ float tile[32][33];
    const float* src = blockIdx.z ? f1 : f0;
    _Float16* dst    = blockIdx.z ? B2 : A2;
    int t = threadIdx.x;
    int n0 = blockIdx.x * 32, c0 = blockIdx.y * 32;
    int tx = t & 31, ty = t >> 5;                    // 32 x 8
#pragma unroll
    for (int u = 0; u < 4; ++u)
        tile[ty + u * 8][tx] = src[(c0 + ty + u * 8) * N0 + n0 + tx];
    __syncthreads();
    int row = t >> 3;            // 0..31 (local n)
    int cg  = (t & 7) * 4;       // 0..28 (local c, groups of 4)
    int n = n0 + row;
    int j = (blockIdx.z ? N0 : 0) + n;
    float s = snorm[j] + snorm[12800 + j];
    float iv = 1.0f / fmaxf(sqrtf(s), 1e-12f);
    union { ushort4 u4; _Float16 h[4]; } pk;
#pragma unroll
    for (int u = 0; u < 4; ++u)
        pk.h[u] = (_Float16)(tile[cg + u][row] * iv);
    *(ushort4*)&dst[n * NC + c0 + cg] = pk.u4;
}

// ---------------- staging: 128 rows x 128 k-values (half-K chunk) -------
__device__ __forceinline__ void stage_chunk(const _Float16* __restrict__ G,
                                            unsigned short* lds, int r0, int kc,
                                            int tid) {
    int rl = tid >> 3;                               // 0..31
    int ch = ((tid & 7) ^ (rl & 7)) * 8;             // swizzled chunk (halves)
#pragma unroll
    for (int kk = 0; kk < 2; ++kk)
#pragma unroll
        for (int g = 0; g < 4; ++g) {
            const _Float16* ga = G + (r0 + g * 32 + rl) * NC + kc * 128 + kk * 64 + ch;
            __builtin_amdgcn_global_load_lds((const GLOBAL_AS unsigned int*)ga,
                (LDS_AS unsigned int*)&lds[kk * 8192 + g * 2048 + tid * 8], 16, 0, 0);
        }
}

// ---------------- half-K compute: 4 s-steps, 64 MFMA/wave ---------------
template<bool HI>
__device__ __forceinline__ void compute_half(const unsigned short* bbuf,
                                             const unsigned short* abufHi,
                                             const half8 aflo[4][4],
                                             int lane, int wm, int wn,
                                             floatx4 acc[4][4]) {
    int q = lane >> 4;
#pragma unroll
    for (int s = 0; s < 4; ++s) {
        int c = s * 4 + q, kk = c >> 3, cq = c & 7;
        half8 af[4], bf[4];
#pragma unroll
        for (int mt = 0; mt < 4; ++mt) {
            int rb = wn * 64 + mt * 16 + (lane & 15);
            bf[mt] = *(const half8*)&bbuf[kk * 8192 + rb * 64 + ((cq ^ (rb & 7)) * 8)];
        }
#pragma unroll
        for (int mt = 0; mt < 4; ++mt) {
            if (HI) {
                int ra = wm * 64 + mt * 16 + (lane & 15);
                af[mt] = *(const half8*)&abufHi[kk * 8192 + ra * 64 + ((cq ^ (ra & 7)) * 8)];
            } else {
                af[mt] = aflo[mt][s];
            }
        }
#pragma unroll
        for (int mt = 0; mt < 4; ++mt)
#pragma unroll
            for (int nt = 0; nt < 4; ++nt)
                acc[mt][nt] = __builtin_amdgcn_mfma_f32_16x16x32_f16(
                    af[mt], bf[nt], acc[mt][nt], 0, 0, 0);
    }
}

// ---------------- shared prologue: stage A, hoist k-low frags -----------
__device__ __forceinline__ void gemm_prologue(const _Float16* __restrict__ A2,
                                              unsigned short* regA,
                                              unsigned short* regB,
                                              int i0, int tid, int lane,
                                              int wm, half8 aflo[4][4]) {
    int q = lane >> 4;
    stage_chunk(A2, regB, i0, 0, tid);               // A k-low (transient)
    stage_chunk(A2, regA, i0, 1, tid);               // A k-high (persistent)
    __syncthreads();
#pragma unroll
    for (int mt = 0; mt < 4; ++mt)
#pragma unroll
        for (int s = 0; s < 4; ++s) {
            int c = s * 4 + q, kk = c >> 3, cq = c & 7;
            int ra = wm * 64 + mt * 16 + (lane & 15);
            aflo[mt][s] = *(const half8*)&regB[kk * 8192 + ra * 64 + ((cq ^ (ra & 7)) * 8)];
        }
    __syncthreads();                                 // regB free
}

// ---------------- K3: GEMM pass 1 — row/col partial sums (unchanged) ----
__global__ __launch_bounds__(256, 2) void kgemm1P(const _Float16* __restrict__ A2,
                                                  const _Float16* __restrict__ B2,
                                                  float* __restrict__ rowpart,
                                                  float* __restrict__ colpart) {
    __shared__ __align__(16) unsigned short lds[32768];   // 64 KiB
    __shared__ float cs[2][128];
    __shared__ float rs[2][128];
    unsigned short* regA = lds;
    unsigned short* regB = lds + 16384;
    int tid = threadIdx.x, lane = tid & 63, wave = tid >> 6;
    int wm = wave & 1, wn = wave >> 1, q = lane >> 4;
    int i0 = blockIdx.x * 128, jp = blockIdx.y * 640;

    half8 aflo[4][4];
    gemm_prologue(A2, regA, regB, i0, tid, lane, wm, aflo);

    float rsum[4][4] = {};
    for (int jt = 0; jt < 5; ++jt) {
        stage_chunk(B2, regB, jp + jt * 128, 0, tid);
        __syncthreads();
        floatx4 acc[4][4] = {};
        compute_half<false>(regB, regA, aflo, lane, wm, wn, acc);
        __syncthreads();
        stage_chunk(B2, regB, jp + jt * 128, 1, tid);
        __syncthreads();
        compute_half<true>(regB, regA, aflo, lane, wm, wn, acc);

        float csum[4] = {0.f, 0.f, 0.f, 0.f};
#pragma unroll
        for (int mt = 0; mt < 4; ++mt)
#pragma unroll
            for (int r = 0; r < 4; ++r) {
                float rv = 0.f;
#pragma unroll
                for (int nt = 0; nt < 4; ++nt) {
                    float e = __expf(10.0f * acc[mt][nt][r]);
                    rv += e; csum[nt] += e;
                }
                rsum[mt][r] += rv;
            }
#pragma unroll
        for (int nt = 0; nt < 4; ++nt) {
            csum[nt] += __shfl_xor(csum[nt], 16);
            csum[nt] += __shfl_xor(csum[nt], 32);
        }
        if (lane < 16)
#pragma unroll
            for (int nt = 0; nt < 4; ++nt)
                cs[wm][wn * 64 + nt * 16 + lane] = csum[nt];
        __syncthreads();                             // regB reads done + cs ready
        if (tid < 128)
            colpart[blockIdx.x * N0 + jp + jt * 128 + tid] = cs[0][tid] + cs[1][tid];
    }
#pragma unroll
    for (int mt = 0; mt < 4; ++mt)
#pragma unroll
        for (int r = 0; r < 4; ++r) {
            float v = rsum[mt][r];
            v += __shfl_xor(v, 1);
            v += __shfl_xor(v, 2);
            v += __shfl_xor(v, 4);
            v += __shfl_xor(v, 8);
            if ((lane & 15) == 0)
                rs[wn][wm * 64 + mt * 16 + q * 4 + r] = v;
        }
    __syncthreads();
    if (tid < 128)
        rowpart[blockIdx.y * N0 + i0 + tid] = rs[0][tid] + rs[1][tid];
}

__global__ __launch_bounds__(256) void kreduce(const float* __restrict__ rowpart,
                                               const float* __restrict__ colpart,
                                               float* __restrict__ rowsum,
                                               float* __restrict__ colsum) {
    int t = blockIdx.x * 256 + threadIdx.x;          // 0..12799
    if (t < N0) {
        float s = 0.f;
#pragma unroll
        for (int y = 0; y < 10; ++y) s += rowpart[y * N0 + t];
        rowsum[t] = s;
    } else {
        int j = t - N0;
        float s = 0.f;
#pragma unroll
        for (int x = 0; x < 50; ++x) s += colpart[x * N0 + j];
        colsum[j] = s;
    }
}

// ---------------- K4: GEMM pass 2 — full-line P stores + log argmax -----
__global__ __launch_bounds__(256, 2) void kgemm2P(const _Float16* __restrict__ A2,
                                                  const _Float16* __restrict__ B2,
                                                  const float* __restrict__ rowsum,
                                                  const float* __restrict__ colsum,
                                                  float* __restrict__ P,
                                                  unsigned long long* __restrict__ rowbpart,
                                                  unsigned long long* __restrict__ colbpart) {
    __shared__ __align__(16) unsigned short lds[32768];   // 64 KiB
    __shared__ unsigned long long cbst[2][128];
    __shared__ unsigned long long rbst[2][128];
    unsigned short* regA = lds;
    unsigned short* regB = lds + 16384;
    int tid = threadIdx.x, lane = tid & 63, wave = tid >> 6;
    int wm = wave & 1, wn = wave >> 1, q = lane >> 4;
    int i0 = blockIdx.x * 128, jp = blockIdx.y * 640;

    half8 aflo[4][4];
    gemm_prologue(A2, regA, regB, i0, tid, lane, wm, aflo);

    float ir[4][4], lr[4][4];                        // recip + log-domain row
#pragma unroll
    for (int mt = 0; mt < 4; ++mt) {
        float4 v4 = *(const float4*)&rowsum[i0 + wm * 64 + mt * 16 + q * 4];
        ir[mt][0] = 1.0f / v4.x; ir[mt][1] = 1.0f / v4.y;
        ir[mt][2] = 1.0f / v4.z; ir[mt][3] = 1.0f / v4.w;
#pragma unroll
        for (int r = 0; r < 4; ++r)
            lr[mt][r] = __logf(ir[mt][r]) * 0.05f + 4.0f;   // ln(ir)/20 + bias
    }

    // per-wave float scratch in regB area: 16 rows x 66 floats (padded)
    float* scr = (float*)lds + 8192 + wave * 1056;

    unsigned long long rbv[4][4] = {};               // row argmax (log-domain)
    for (int jt = 0; jt < 5; ++jt) {
        stage_chunk(B2, regB, jp + jt * 128, 0, tid);
        __syncthreads();
        floatx4 acc[4][4] = {};
        compute_half<false>(regB, regA, aflo, lane, wm, wn, acc);
        __syncthreads();
        stage_chunk(B2, regB, jp + jt * 128, 1, tid);
        __syncthreads();
        compute_half<true>(regB, regA, aflo, lane, wm, wn, acc);

        int jcb = jp + jt * 128 + wn * 64;
        int cb0 = jcb + (lane & 15);
        float ic[4], lc[4];
#pragma unroll
        for (int nt = 0; nt < 4; ++nt) {
            ic[nt] = 1.0f / colsum[cb0 + nt * 16];
            lc[nt] = __logf(ic[nt]) * 0.05f + 4.0f;  // ln(ic)/20 + bias
        }

        unsigned long long colb[4] = {0ull, 0ull, 0ull, 0ull};
#pragma unroll
        for (int mt = 0; mt < 4; ++mt) {
            int rb0 = i0 + wm * 64 + mt * 16 + q * 4;
#pragma unroll
            for (int r = 0; r < 4; ++r) {
                int row = rb0 + r;
                float lrr = lr[mt][r];
#pragma unroll
                for (int nt = 0; nt < 4; ++nt) {
                    float a  = acc[mt][nt][r];
                    float pv = __expf(20.0f * a) * ir[mt][r] * ic[nt];
                    scr[(q * 4 + r) * 66 + (lane & 15) + nt * 16] = pv;
                    unsigned long long pr = packvi(a + lc[nt], cb0 + nt * 16);
                    if (pr > rbv[mt][r]) rbv[mt][r] = pr;
                    unsigned long long pc = packvi(a + lrr, row);
                    if (pc > colb[nt]) colb[nt] = pc;
                }
            }
            // read back transposed: 4 consecutive floats/lane -> dwordx4 nt
#pragma unroll
            for (int g = 0; g < 4; ++g) {
                floatx4 o = *(const floatx4*)&scr[(g * 4 + (lane >> 4)) * 66 + (lane & 15) * 4];
                int row = i0 + wm * 64 + mt * 16 + g * 4 + (lane >> 4);
                __builtin_nontemporal_store(o, (floatx4*)&P[row * N0 + jcb + (lane & 15) * 4]);
            }
        }
#pragma unroll
        for (int nt = 0; nt < 4; ++nt) {
            unsigned long long o = __shfl_xor(colb[nt], 16);
            if (o > colb[nt]) colb[nt] = o;
            o = __shfl_xor(colb[nt], 32);
            if (o > colb[nt]) colb[nt] = o;
        }
        if (lane < 16)
#pragma unroll
            for (int nt = 0; nt < 4; ++nt)
                cbst[wm][wn * 64 + nt * 16 + lane] = colb[nt];
        __syncthreads();                             // scratch reads done too
        if (tid < 128) {
            unsigned long long a = cbst[0][tid], b = cbst[1][tid];
            colbpart[blockIdx.x * N0 + jp + jt * 128 + tid] = (a > b) ? a : b;
        }
    }
#pragma unroll
    for (int mt = 0; mt < 4; ++mt)
#pragma unroll
        for (int r = 0; r < 4; ++r) {
            unsigned long long v = rbv[mt][r];
#pragma unroll
            for (int s = 1; s < 16; s <<= 1) {
                unsigned long long o = __shfl_xor(v, s);
                if (o > v) v = o;
            }
            if ((lane & 15) == 0)
                rbst[wn][wm * 64 + mt * 16 + q * 4 + r] = v;
        }
    __syncthreads();
    if (tid < 128) {
        unsigned long long a = rbst[0][tid], b = rbst[1][tid];
        rowbpart[blockIdx.y * N0 + i0 + tid] = (a > b) ? a : b;
    }
}

// ---------------- K5: reduce argmax partials + mutual-NN outputs --------
__global__ __launch_bounds__(256) void kmatchP(const unsigned long long* __restrict__ rowbpart,
                                               const unsigned long long* __restrict__ colbpart,
                                               const float* __restrict__ P,
                                               float* __restrict__ out) {
    int i = blockIdx.x * 256 + threadIdx.x;      // 0..6399
    unsigned long long rb = 0ull;
#pragma unroll
    for (int y = 0; y < 10; ++y) {
        unsigned long long v = rowbpart[y * N0 + i];
        if (v > rb) rb = v;
    }
    int jj = (int)(rb & 0xffffffffu);
    unsigned long long cb = 0ull;
    for (int x = 0; x < 50; ++x) {
        unsigned long long v = colbpart[x * N0 + jj];
        if (v > cb) cb = v;
    }
    int i2 = (int)(cb & 0xffffffffu);
    float conf = P[i * N0 + jj];                 // recover max P value
    bool valid = (i2 == i) && (conf > 0.2f);
    float vf = valid ? 1.0f : 0.0f;

    float* mk0   = out + 40960000;
    float* mk1   = out + 40972800;
    float* mconf = out + 40985600;
    float* vout  = out + 40992000;
    mk0[i * 2 + 0] = vf * (float)(i % WW);
    mk0[i * 2 + 1] = vf * (float)(i / WW);
    mk1[i * 2 + 0] = vf * (float)(jj % WW);
    mk1[i * 2 + 1] = vf * (float)(jj / WW);
    mconf[i] = valid ? conf : 0.0f;
    vout[i]  = vf;
}

extern "C" void kernel_launch(void* const* d_in, const int* in_sizes, int n_in,
                              void* d_out, int out_size, void* d_ws, size_t ws_size,
                              hipStream_t stream) {
    const float* f0 = (const float*)d_in[0];
    const float* f1 = (const float*)d_in[1];
    float* out = (float*)d_out;

    _Float16* A2 = (_Float16*)d_ws;                  // 6400x256 fp16
    _Float16* B2 = A2 + 6400 * 256;
    float* snorm   = (float*)(B2 + 6400 * 256);      // 25600 partial sumsq
    float* rowsum  = snorm + 25600;                  // 6400
    float* colsum  = rowsum + 6400;                  // 6400
    float* rowpart = colsum + 6400;                  // 10 x 6400
    float* colpart = rowpart + 10 * 6400;            // 50 x 6400
    unsigned long long* rowbpart =                   // 10 x 6400 (8B aligned)
        (unsigned long long*)(colpart + 50 * 6400);
    unsigned long long* colbpart = rowbpart + 10 * 6400;   // 50 x 6400

    knorm<<<100, 256, 0, stream>>>(f0, f1, snorm);
    ktrans<<<dim3(200, 8, 2), 256, 0, stream>>>(f0, f1, snorm, A2, B2);
    kgemm1P<<<dim3(50, 10), 256, 0, stream>>>(A2, B2, rowpart, colpart);
    kreduce<<<50, 256, 0, stream>>>(rowpart, colpart, rowsum, colsum);
    kgemm2P<<<dim3(50, 10), 256, 0, stream>>>(A2, B2, rowsum, colsum,
                                              out, rowbpart, colbpart);
    kmatchP<<<25, 256, 0, stream>>>(rowbpart, colbpart, out, out);
}

// Round 9
// 276.786 us; speedup vs baseline: 1.0631x; 1.0295x over previous
//
#include <hip/hip_runtime.h>

#define N0 6400
#define NC 256
#define WW 80

using half8   = __attribute__((ext_vector_type(8))) _Float16;
using floatx4 = __attribute__((ext_vector_type(4))) float;
#define GLOBAL_AS __attribute__((address_space(1)))
#define LDS_AS    __attribute__((address_space(3)))

__device__ __forceinline__ unsigned long long packvi(float v, int i) {
    return ((unsigned long long)__float_as_uint(v) << 32) | (unsigned int)i;
}

// ---------------- K1: partial sumsq over channel halves -----------------
__global__ __launch_bounds__(256) void knorm(const float* __restrict__ f0,
                                             const float* __restrict__ f1,
                                             float* __restrict__ snorm) {
    int g = blockIdx.x * 256 + threadIdx.x;          // 0..25599
    int h = (g >= 12800) ? 1 : 0;
    int j = g - h * 12800;                           // 0..12799
    const float* src = (j < N0) ? f0 : f1;
    int n = (j < N0) ? j : (j - N0);
    int c0 = h * 128;
    float s = 0.f;
#pragma unroll 8
    for (int c = 0; c < 128; ++c) {
        float v = src[(c0 + c) * N0 + n];
        s += v * v;
    }
    snorm[g] = s;
}

// -------- K2: transpose (C,N)->(N,256) fp16, normalized; z selects f0/f1
__global__ __launch_bounds__(256) void ktrans(const float* __restrict__ f0,
                                              const float* __restrict__ f1,
                                              const float* __restrict__ snorm,
                                              _Float16* __restrict__ A2,
                                              _Float16* __restrict__ B2) {
    __shared__ float tile[32][33];
    const float* src = blockIdx.z ? f1 : f0;
    _Float16* dst    = blockIdx.z ? B2 : A2;
    int t = threadIdx.x;
    int n0 = blockIdx.x * 32, c0 = blockIdx.y * 32;
    int tx = t & 31, ty = t >> 5;                    // 32 x 8
#pragma unroll
    for (int u = 0; u < 4; ++u)
        tile[ty + u * 8][tx] = src[(c0 + ty + u * 8) * N0 + n0 + tx];
    __syncthreads();
    int row = t >> 3;            // 0..31 (local n)
    int cg  = (t & 7) * 4;       // 0..28 (local c, groups of 4)
    int n = n0 + row;
    int j = (blockIdx.z ? N0 : 0) + n;
    float s = snorm[j] + snorm[12800 + j];
    float iv = 1.0f / fmaxf(sqrtf(s), 1e-12f);
    union { ushort4 u4; _Float16 h[4]; } pk;
#pragma unroll
    for (int u = 0; u < 4; ++u)
        pk.h[u] = (_Float16)(tile[cg + u][row] * iv);
    *(ushort4*)&dst[n * NC + c0 + cg] = pk.u4;
}

// -------- staging: 128 rows x 256 k (full-K, 64 KiB), 512 threads -------
// LDS layout [kk(4)][row(128)][64 halves]; 16B chunk at (chunk ^ (row&7)),
// swizzle applied to the GLOBAL source so LDS dest stays lane-linear.
__device__ __forceinline__ void stage_full(const _Float16* __restrict__ G,
                                           unsigned short* lds, int r0, int tid) {
    int rl = tid >> 3;                               // 0..63
    int ch = ((tid & 7) ^ (rl & 7)) * 8;             // swizzled chunk (halves)
#pragma unroll
    for (int kk = 0; kk < 4; ++kk)
#pragma unroll
        for (int g = 0; g < 2; ++g) {
            const _Float16* ga = G + (r0 + g * 64 + rl) * NC + kk * 64 + ch;
            __builtin_amdgcn_global_load_lds((const GLOBAL_AS unsigned int*)ga,
                (LDS_AS unsigned int*)&lds[kk * 8192 + g * 4096 + tid * 8], 16, 0, 0);
        }
}

// -------- full-K compute, SWAPPED operands: acc = mfma(bf, af) ---------
// D: lane&15 -> P row (af rows), (lane>>4)*4+reg -> P col (bf rows).
__device__ __forceinline__ void compute_tile(const unsigned short* cur,
                                             const half8 af[4][8],
                                             int lane, int wn,
                                             floatx4 acc[4][2]) {
    int q = lane >> 4;
    int rb0 = wn * 32 + (lane & 15), rb1 = rb0 + 16;
#pragma unroll
    for (int s = 0; s < 8; ++s) {
        int c = s * 4 + q, kk = c >> 3, cq = c & 7;
        half8 bf0 = *(const half8*)&cur[kk * 8192 + rb0 * 64 + ((cq ^ (rb0 & 7)) * 8)];
        half8 bf1 = *(const half8*)&cur[kk * 8192 + rb1 * 64 + ((cq ^ (rb1 & 7)) * 8)];
#pragma unroll
        for (int at = 0; at < 4; ++at) {
            acc[at][0] = __builtin_amdgcn_mfma_f32_16x16x32_f16(bf0, af[at][s], acc[at][0], 0, 0, 0);
            acc[at][1] = __builtin_amdgcn_mfma_f32_16x16x32_f16(bf1, af[at][s], acc[at][1], 0, 0, 0);
        }
    }
}

// -------- shared prologue: A panel -> regs, first B tile staged --------
__device__ __forceinline__ void gemm_prologue(const _Float16* __restrict__ A2,
                                              const _Float16* __restrict__ B2,
                                              unsigned short* lds,
                                              int i0, int jp, int tid, int lane,
                                              int wm, half8 af[4][8]) {
    int q = lane >> 4;
    stage_full(A2, lds, i0, tid);                    // A -> lo half
    __syncthreads();
#pragma unroll
    for (int at = 0; at < 4; ++at)
#pragma unroll
        for (int s = 0; s < 8; ++s) {
            int c = s * 4 + q, kk = c >> 3, cq = c & 7;
            int ra = wm * 64 + at * 16 + (lane & 15);
            af[at][s] = *(const half8*)&lds[kk * 8192 + ra * 64 + ((cq ^ (ra & 7)) * 8)];
        }
    stage_full(B2, lds + 32768, jp, tid);            // B tile 0 -> hi half
    __syncthreads();                                 // af in regs; B0 ready
}

// ---------------- K3: GEMM pass 1 — row/col partial sums ----------------
// Grid (50,5), 512 thr, 1 block/CU, 128 KiB LDS, B double-buffered with
// stage-ahead; ONE barrier per j-tile. Partials to per-wave global slots.
__global__ __launch_bounds__(512, 2) void kgemm1N(const _Float16* __restrict__ A2,
                                                  const _Float16* __restrict__ B2,
                                                  float* __restrict__ rowpart,
                                                  float* __restrict__ colpart) {
    __shared__ __align__(16) unsigned short lds[65536];   // 128 KiB
    int tid = threadIdx.x, lane = tid & 63, wave = tid >> 6;
    int wm = wave & 1, wn = wave >> 1, q = lane >> 4;
    int i0 = blockIdx.x * 128, jp = blockIdx.y * 1280;

    half8 af[4][8];
    gemm_prologue(A2, B2, lds, i0, jp, tid, lane, wm, af);

    float rsum[4] = {0.f, 0.f, 0.f, 0.f};
    for (int jt = 0; jt < 10; ++jt) {
        unsigned short* cur = lds + ((jt & 1) ? 0 : 32768);
        if (jt < 9)                                  // stage-ahead, other buf
            stage_full(B2, lds + ((jt & 1) ? 32768 : 0), jp + (jt + 1) * 128, tid);

        floatx4 acc[4][2] = {};
        compute_tile(cur, af, lane, wn, acc);

        int jcb = jp + jt * 128;
        float csum[2][4] = {};
#pragma unroll
        for (int at = 0; at < 4; ++at)
#pragma unroll
            for (int bt = 0; bt < 2; ++bt)
#pragma unroll
                for (int r = 0; r < 4; ++r) {
                    float e = __expf(10.0f * acc[at][bt][r]);
                    rsum[at] += e;                   // row = at*16+(lane&15)
                    csum[bt][r] += e;                // col = wn*32+bt*16+q*4+r
                }
#pragma unroll
        for (int bt = 0; bt < 2; ++bt)
#pragma unroll
            for (int r = 0; r < 4; ++r) {
                float v = csum[bt][r];
                v += __shfl_xor(v, 1);
                v += __shfl_xor(v, 2);
                v += __shfl_xor(v, 4);
                v += __shfl_xor(v, 8);
                if ((lane & 15) == 0)
                    colpart[(blockIdx.x * 2 + wm) * N0 + jcb + wn * 32 + bt * 16 + q * 4 + r] = v;
            }
        __syncthreads();                             // cur reads done + stage drained
    }
#pragma unroll
    for (int at = 0; at < 4; ++at) {
        float v = rsum[at];
        v += __shfl_xor(v, 16);
        v += __shfl_xor(v, 32);
        if (lane < 16)
            rowpart[(blockIdx.y * 4 + wn) * N0 + i0 + wm * 64 + at * 16 + lane] = v;
    }
}

// ---------------- K3.5: fold partials into rowsum / colsum --------------
__global__ __launch_bounds__(256) void kreduce(const float* __restrict__ rowpart,
                                               const float* __restrict__ colpart,
                                               float* __restrict__ rowsum,
                                               float* __restrict__ colsum) {
    int t = blockIdx.x * 256 + threadIdx.x;          // 0..12799
    if (t < N0) {
        float s = 0.f;
#pragma unroll
        for (int k = 0; k < 20; ++k) s += rowpart[k * N0 + t];
        rowsum[t] = s;
    } else {
        int j = t - N0;
        float s = 0.f;
        for (int k = 0; k < 100; ++k) s += colpart[k * N0 + j];
        colsum[j] = s;
    }
}

// ---------------- K4: GEMM pass 2 — direct P stores + log argmax --------
__global__ __launch_bounds__(512, 2) void kgemm2N(const _Float16* __restrict__ A2,
                                                  const _Float16* __restrict__ B2,
                                                  const float* __restrict__ rowsum,
                                                  const float* __restrict__ colsum,
                                                  float* __restrict__ P,
                                                  unsigned long long* __restrict__ rowbpart,
                                                  unsigned long long* __restrict__ colbpart) {
    __shared__ __align__(16) unsigned short lds[65536];   // 128 KiB
    int tid = threadIdx.x, lane = tid & 63, wave = tid >> 6;
    int wm = wave & 1, wn = wave >> 1, q = lane >> 4;
    int i0 = blockIdx.x * 128, jp = blockIdx.y * 1280;

    half8 af[4][8];
    gemm_prologue(A2, B2, lds, i0, jp, tid, lane, wm, af);

    float ir[4], lr[4];                              // per-lane row (lane&15)
#pragma unroll
    for (int at = 0; at < 4; ++at) {
        ir[at] = 1.0f / rowsum[i0 + wm * 64 + at * 16 + (lane & 15)];
        lr[at] = __logf(ir[at]) * 0.05f + 4.0f;      // ln(ir)/20 + bias
    }

    unsigned long long rbv[4] = {};                  // row argmax (log-domain)
    for (int jt = 0; jt < 10; ++jt) {
        unsigned short* cur = lds + ((jt & 1) ? 0 : 32768);
        if (jt < 9)
            stage_full(B2, lds + ((jt & 1) ? 32768 : 0), jp + (jt + 1) * 128, tid);

        floatx4 acc[4][2] = {};
        compute_tile(cur, af, lane, wn, acc);

        int jcb = jp + jt * 128;
        float ic[2][4], lc[2][4];
#pragma unroll
        for (int bt = 0; bt < 2; ++bt) {
            float4 c4 = *(const float4*)&colsum[jcb + wn * 32 + bt * 16 + q * 4];
            ic[bt][0] = 1.0f / c4.x; ic[bt][1] = 1.0f / c4.y;
            ic[bt][2] = 1.0f / c4.z; ic[bt][3] = 1.0f / c4.w;
#pragma unroll
            for (int r = 0; r < 4; ++r)
                lc[bt][r] = __logf(ic[bt][r]) * 0.05f + 4.0f;
        }

        unsigned long long colb[2][4] = {};
#pragma unroll
        for (int at = 0; at < 4; ++at) {
            int row = i0 + wm * 64 + at * 16 + (lane & 15);
#pragma unroll
            for (int bt = 0; bt < 2; ++bt) {
                floatx4 pv;
#pragma unroll
                for (int r = 0; r < 4; ++r) {
                    float a = acc[at][bt][r];
                    pv[r] = __expf(20.0f * a) * ir[at] * ic[bt][r];
                    unsigned long long pr = packvi(a + lc[bt][r],
                                                   jcb + wn * 32 + bt * 16 + q * 4 + r);
                    if (pr > rbv[at]) rbv[at] = pr;
                    unsigned long long pc = packvi(a + lr[at], row);
                    if (pc > colb[bt][r]) colb[bt][r] = pc;
                }
                __builtin_nontemporal_store(pv,
                    (floatx4*)&P[row * N0 + jcb + wn * 32 + bt * 16 + q * 4]);
            }
        }
#pragma unroll
        for (int bt = 0; bt < 2; ++bt)
#pragma unroll
            for (int r = 0; r < 4; ++r) {
                unsigned long long v = colb[bt][r];
#pragma unroll
                for (int s = 1; s < 16; s <<= 1) {
                    unsigned long long o = __shfl_xor(v, s);
                    if (o > v) v = o;
                }
                if ((lane & 15) == 0)
                    colbpart[(blockIdx.x * 2 + wm) * N0 + jcb + wn * 32 + bt * 16 + q * 4 + r] = v;
            }
        __syncthreads();
    }
#pragma unroll
    for (int at = 0; at < 4; ++at) {
        unsigned long long v = rbv[at];
        unsigned long long o = __shfl_xor(v, 16);
        if (o > v) v = o;
        o = __shfl_xor(v, 32);
        if (o > v) v = o;
        if (lane < 16)
            rowbpart[(blockIdx.y * 4 + wn) * N0 + i0 + wm * 64 + at * 16 + lane] = v;
    }
}

// ---------------- K4.5: fold argmax partials -> rowbest / colbest -------
__global__ __launch_bounds__(256) void kreduceB(const unsigned long long* __restrict__ rowbpart,
                                                const unsigned long long* __restrict__ colbpart,
                                                unsigned long long* __restrict__ rowbest,
                                                unsigned long long* __restrict__ colbest) {
    int t = blockIdx.x * 256 + threadIdx.x;          // 0..12799
    if (t < N0) {
        unsigned long long m = 0ull;
#pragma unroll
        for (int k = 0; k < 20; ++k) {
            unsigned long long v = rowbpart[k * N0 + t];
            if (v > m) m = v;
        }
        rowbest[t] = m;
    } else {
        int j = t - N0;
        unsigned long long m = 0ull;
        for (int k = 0; k < 100; ++k) {
            unsigned long long v = colbpart[k * N0 + j];
            if (v > m) m = v;
        }
        colbest[j] = m;
    }
}

// ---------------- K5: mutual-NN matching outputs -----------------------
__global__ __launch_bounds__(256) void kmatch(const unsigned long long* __restrict__ rowbest,
                                              const unsigned long long* __restrict__ colbest,
                                              const float* __restrict__ P,
                                              float* __restrict__ out) {
    int i = blockIdx.x * 256 + threadIdx.x;      // 0..6399
    unsigned long long rb = rowbest[i];
    int jj = (int)(rb & 0xffffffffu);
    unsigned long long cb = colbest[jj];
    int i2 = (int)(cb & 0xffffffffu);
    float conf = P[i * N0 + jj];                 // recover max P value
    bool valid = (i2 == i) && (conf > 0.2f);
    float vf = valid ? 1.0f : 0.0f;

    float* mk0   = out + 40960000;
    float* mk1   = out + 40972800;
    float* mconf = out + 40985600;
    float* vout  = out + 40992000;
    mk0[i * 2 + 0] = vf * (float)(i % WW);
    mk0[i * 2 + 1] = vf * (float)(i / WW);
    mk1[i * 2 + 0] = vf * (float)(jj % WW);
    mk1[i * 2 + 1] = vf * (float)(jj / WW);
    mconf[i] = valid ? conf : 0.0f;
    vout[i]  = vf;
}

extern "C" void kernel_launch(void* const* d_in, const int* in_sizes, int n_in,
                              void* d_out, int out_size, void* d_ws, size_t ws_size,
                              hipStream_t stream) {
    const float* f0 = (const float*)d_in[0];
    const float* f1 = (const float*)d_in[1];
    float* out = (float*)d_out;

    _Float16* A2 = (_Float16*)d_ws;                  // 6400x256 fp16
    _Float16* B2 = A2 + 6400 * 256;
    // u64 region (8B-aligned: 6,553,600 % 8 == 0)
    unsigned long long* rowbpart = (unsigned long long*)(B2 + 6400 * 256); // 20x6400
    unsigned long long* colbpart = rowbpart + 20 * 6400;                   // 100x6400
    unsigned long long* rowbest  = colbpart + 100 * 6400;                  // 6400
    unsigned long long* colbest  = rowbest + 6400;                         // 6400
    // f32 region
    float* snorm   = (float*)(colbest + 6400);       // 25600
    float* rowsum  = snorm + 25600;                  // 6400
    float* colsum  = rowsum + 6400;                  // 6400
    float* rowpart = colsum + 6400;                  // 20 x 6400
    float* colpart = rowpart + 20 * 6400;            // 100 x 6400

    knorm<<<100, 256, 0, stream>>>(f0, f1, snorm);
    ktrans<<<dim3(200, 8, 2), 256, 0, stream>>>(f0, f1, snorm, A2, B2);
    kgemm1N<<<dim3(50, 5), 512, 0, stream>>>(A2, B2, rowpart, colpart);
    kreduce<<<50, 256, 0, stream>>>(rowpart, colpart, rowsum, colsum);
    kgemm2N<<<dim3(50, 5), 512, 0, stream>>>(A2, B2, rowsum, colsum,
                                             out, rowbpart, colbpart);
    kreduceB<<<50, 256, 0, stream>>>(rowbpart, colbpart, rowbest, colbest);
    kmatch<<<25, 256, 0, stream>>>(rowbest, colbest, out, out);
}